// Round 17
// baseline (183.502 us; speedup 1.0000x reference)
//
#include <hip/hip_runtime.h>
#include <stdint.h>

#define SEQ   2048
#define NB    2
#define LDQKV 3072
#define HD    128
// 1/sqrt(128) * log2(e): QK^T scores land in base-2 domain -> exp2 directly.
#define QSCALE2 (0.08838834764831845f * 1.44269504088896340f)

typedef __attribute__((ext_vector_type(8))) short short8;
typedef __attribute__((ext_vector_type(4))) short short4v;
typedef __attribute__((ext_vector_type(4))) float f32x4;
typedef __attribute__((ext_vector_type(16))) float f32x16;
typedef __attribute__((ext_vector_type(4))) unsigned int u32x4;
typedef __attribute__((ext_vector_type(2))) unsigned int u32x2;
typedef __attribute__((ext_vector_type(8))) __bf16 bf16x8;

__device__ __forceinline__ float bs2f(short s) {
  unsigned int u = ((unsigned int)(unsigned short)s) << 16;
  return __builtin_bit_cast(float, u);
}
__device__ __forceinline__ short f2bs(float f) {
  unsigned int u = __builtin_bit_cast(unsigned int, f);
  u += 0x7fffu + ((u >> 16) & 1u);
  return (short)(u >> 16);
}
__device__ __forceinline__ unsigned int cvt_pk(float lo, float hi) {
  unsigned int r;
  asm("v_cvt_pk_bf16_f32 %0, %1, %2" : "=v"(r) : "v"(lo), "v"(hi));
  return r;
}
// bare v_exp_f32 (2^x): avoids ocml exp2f edge-handling (~15 VALU each)
__device__ __forceinline__ float fexp2(float x) {
  float r;
  asm("v_exp_f32 %0, %1" : "=v"(r) : "v"(x));
  return r;
}
__device__ __forceinline__ f32x4 mfma16(short8 a, short8 b, f32x4 c) {
  return __builtin_amdgcn_mfma_f32_16x16x32_bf16(
      __builtin_bit_cast(bf16x8, a), __builtin_bit_cast(bf16x8, b), c, 0, 0, 0);
}
__device__ __forceinline__ f32x16 mfma32(short8 a, short8 b, f32x16 c) {
  return __builtin_amdgcn_mfma_f32_32x32x16_bf16(
      __builtin_bit_cast(bf16x8, a), __builtin_bit_cast(bf16x8, b), c, 0, 0, 0);
}
__device__ __forceinline__ void gload_lds16(const void* g, void* l) {
  __builtin_amdgcn_global_load_lds(
      (__attribute__((address_space(1))) const void*)(uintptr_t)g,
      (__attribute__((address_space(3))) void*)(unsigned int)(uintptr_t)l,
      16, 0, 0);
}

#define SBAR() asm volatile("s_barrier" ::: "memory")
#define VMC(n) asm volatile("s_waitcnt vmcnt(" #n ")" ::: "memory")

// ---- fused prep: x fp32->bf16 convert + 4 weight transposes, 1D grid ----
__global__ __launch_bounds__(256) void k_prep(const float* __restrict__ x,
                                              const float* __restrict__ wq,
                                              const float* __restrict__ wk,
                                              const float* __restrict__ wv,
                                              const float* __restrict__ wo,
                                              short* __restrict__ xb,
                                              short* __restrict__ wT,
                                              short* __restrict__ woT) {
  __shared__ __align__(16) float tile[64][68];
  const int bid = blockIdx.x, t = threadIdx.x;
  if (bid < 4096) {  // cvt
    int i = bid * 256 + t;
    f32x4 a = *(const f32x4*)(x + (size_t)i * 8);
    f32x4 b = *(const f32x4*)(x + (size_t)i * 8 + 4);
    short8 o;
#pragma unroll
    for (int j = 0; j < 4; ++j) { o[j] = f2bs(a[j]); o[4 + j] = f2bs(b[j]); }
    *(short8*)(xb + (size_t)i * 8) = o;
    return;
  }
  const float* src;
  short* dst;
  int N, id;
  if (bid < 5120)      { id = bid - 4096; src = wq; dst = wT;                        N = 2048; }
  else if (bid < 5376) { id = bid - 5120; src = wk; dst = wT + (size_t)2048 * 2048;  N = 512;  }
  else if (bid < 5632) { id = bid - 5376; src = wv; dst = wT + (size_t)2560 * 2048;  N = 512;  }
  else                 { id = bid - 5632; src = wo; dst = woT;                       N = 2048; }
  const int K = 2048;
  int k0 = (id & 31) * 64, n0 = (id >> 5) * 64;
#pragma unroll
  for (int rep = 0; rep < 4; ++rep) {
    int lin = rep * 1024 + t * 4;
    int kk = lin >> 6, nn = lin & 63;
    f32x4 v = *(const f32x4*)(src + (size_t)(k0 + kk) * N + n0 + nn);
    *(f32x4*)(&tile[kk][nn]) = v;
  }
  __syncthreads();
#pragma unroll
  for (int rep = 0; rep < 4; ++rep) {
    int lin = rep * 1024 + t * 4;
    int nn = lin >> 6, kk = lin & 63;
    short4v o;
#pragma unroll
    for (int j = 0; j < 4; ++j) o[j] = f2bs(tile[kk + j][nn]);
    *(short4v*)(dst + (size_t)(n0 + nn) * K + k0 + kk) = o;
  }
}

// ------- GEMM 256x(NH*128) tile, 2-barrier/K-tile, interleaved reads ----
// NH=2 body: prefetch-issue first, then rdA0+rdB0 -> MFMA(0,0) -> rdB1+rdA1
// -> MFMA(0,1) -> SBAR -> late stages -> MFMA(1,0) -> MFMA(1,1) -> VMC -> SBAR.
// Same per-tile stage counts as R14 (vmcnt ledger identical).
template <int NH, int FP32OUT, int ROPE>
__global__ __launch_bounds__(512, 2) void k_gemm256(const short* __restrict__ A,
                                                    const short* __restrict__ Bt,
                                                    void* __restrict__ Cp,
                                                    const float* __restrict__ fcos,
                                                    const float* __restrict__ fsin,
                                                    int M, int N, int K) {
  __shared__ short Al[2][2][128 * 64];
  __shared__ short Bl[2][NH][128 * 64];
  const int t = threadIdx.x, l = t & 63, w = t >> 6;
  const int pm = w >> 2, pn = w & 3;
  const int lrow = l & 15, lg = l >> 4;
  const int NT = K >> 6;

  const int nbm = M >> 8;
  const int per = gridDim.x >> 3;
  const int id2 = (blockIdx.x & 7) * per + (blockIdx.x >> 3);
  const int m0 = (id2 % nbm) * 256, n0 = (id2 / nbm) * (NH * 128);

  const int srow = w * 8 + (l >> 3);
  const int sgx = ((l & 7) ^ (srow & 7)) * 8;
  const short* Abase = A + (size_t)(m0 + srow) * K + sgx;
  const short* Bbase = Bt + (size_t)(n0 + srow) * K + sgx;

  f32x4 acc[8][NH * 2] = {};
  short8 aFr0[4][2], aFr1[4][2], bFr[NH][2][2];

  auto stgA = [&](int d, int h, int tv) {
    const short* g = Abase + (size_t)(h * 128) * K + (size_t)tv * 64;
    gload_lds16(g, &Al[d][h][w * 512]);
    gload_lds16(g + (size_t)64 * K, &Al[d][h][w * 512 + 4096]);
  };
  auto stgB = [&](int d, int h, int tv) {
    const short* g = Bbase + (size_t)(h * 128) * K + (size_t)tv * 64;
    gload_lds16(g, &Bl[d][h][w * 512]);
    gload_lds16(g + (size_t)64 * K, &Bl[d][h][w * 512 + 4096]);
  };
  auto rdA = [&](int d, int Mh, short8 (*dst)[2]) {
#pragma unroll
    for (int mi = 0; mi < 4; ++mi) {
      int rl = pm * 64 + mi * 16 + lrow;
#pragma unroll
      for (int kk = 0; kk < 2; ++kk)
        dst[mi][kk] = *(const short8*)&Al[d][Mh][rl * 64 +
                                                 (((kk * 4 + lg) ^ (rl & 7)) * 8)];
    }
  };
  auto rdBh = [&](int d, int h) {
#pragma unroll
    for (int ni = 0; ni < 2; ++ni) {
      int rl = pn * 32 + ni * 16 + lrow;
#pragma unroll
      for (int kk = 0; kk < 2; ++kk)
        bFr[h][ni][kk] =
            *(const short8*)&Bl[d][h][rl * 64 +
                                      (((kk * 4 + lg) ^ (rl & 7)) * 8)];
    }
  };

#define MMQ(Mh, Nh, FR)                                                      \
  do {                                                                       \
    __builtin_amdgcn_s_setprio(1);                                           \
    _Pragma("unroll") for (int mi = 0; mi < 4; ++mi)                         \
        _Pragma("unroll") for (int ni = 0; ni < 2; ++ni)                     \
            _Pragma("unroll") for (int kk = 0; kk < 2; ++kk)                 \
                acc[(Mh)*4 + mi][(Nh)*2 + ni] =                              \
                    mfma16(FR[mi][kk], bFr[Nh][ni][kk],                      \
                           acc[(Mh)*4 + mi][(Nh)*2 + ni]);                   \
    __builtin_amdgcn_s_setprio(0);                                           \
  } while (0)

  // prologue: tile-0 fully staged; late-slots for tile 1 in flight
  stgA(0, 0, 0);
  for (int h = 0; h < NH; ++h) stgB(0, h, 0);
  stgA(0, 1, 0);
  stgA(1, 0, 1);
  if (NH == 2) stgB(1, 1, 1);
  if (NH == 2) { VMC(4); } else { VMC(2); }
  SBAR();

  for (int v = 0; v < NT; ++v) {
    const int d = v & 1, d1 = d ^ 1;
    // issue next-tile prefetch first (earliest latency cover)
    if (v + 1 < NT) { stgB(d1, 0, v + 1); stgA(d1, 1, v + 1); }
    rdA(d, 0, aFr0);
    rdBh(d, 0);
    MMQ(0, 0, aFr0);
    if (NH == 2) {
      rdBh(d, 1);
      rdA(d, 1, aFr1);
      MMQ(0, 1, aFr0);
    } else {
      rdA(d, 1, aFr1);
    }
    SBAR();  // all waves' d-slot reads done -> d slots may be overwritten
    if (v + 2 < NT) {
      stgA(d, 0, v + 2);
      if (NH == 2) stgB(d, 1, v + 2);
    }
    MMQ(1, 0, aFr1);
    if (NH == 2) MMQ(1, 1, aFr1);
    if (v + 2 < NT) {
      if (NH == 2) { VMC(4); } else { VMC(2); }
    } else {
      VMC(0);
    }
    SBAR();
  }
#undef MMQ

  // epilogue (rope gating is block-uniform: regions are 256-aligned)
  const bool doRope = ROPE && (n0 < 2560);
  const float qs = (n0 < 2048) ? QSCALE2 : 1.0f;
  const int p0i = (pn * 32 + lrow) >> 1;  // ni=0 pair index; ni=1 -> +8
  const bool ev = ((lrow & 1) == 0);
#pragma unroll
  for (int Mh = 0; Mh < 2; ++Mh)
#pragma unroll
    for (int mi = 0; mi < 4; ++mi) {
      const int row = m0 + Mh * 128 + pm * 64 + mi * 16 + lg * 4;
      float cc[4][2], ss[4][2];
      if (doRope) {
#pragma unroll
        for (int v2 = 0; v2 < 4; ++v2)
#pragma unroll
          for (int ni = 0; ni < 2; ++ni) {
            cc[v2][ni] = fcos[(size_t)(row + v2) * 64 + p0i + ni * 8] * qs;
            ss[v2][ni] = fsin[(size_t)(row + v2) * 64 + p0i + ni * 8] * qs;
          }
      }
#pragma unroll
      for (int h = 0; h < NH; ++h)
#pragma unroll
        for (int ni = 0; ni < 2; ++ni) {
          int col = n0 + h * 128 + pn * 32 + ni * 16 + lrow;
          f32x4 vv = acc[Mh * 4 + mi][h * 2 + ni];
          if (doRope) {
#pragma unroll
            for (int v2 = 0; v2 < 4; ++v2) {
              float xx = vv[v2];
              float xp = __shfl_xor(xx, 1);
              vv[v2] = ev ? (xx * cc[v2][ni] - xp * ss[v2][ni])
                          : (xp * ss[v2][ni] + xx * cc[v2][ni]);
            }
          }
#pragma unroll
          for (int v2 = 0; v2 < 4; ++v2) {
            if constexpr (FP32OUT)
              ((float*)Cp)[(size_t)(row + v2) * N + col] = vv[v2];
            else
              ((short*)Cp)[(size_t)(row + v2) * N + col] = f2bs(vv[v2]);
          }
        }
    }
}

// ---- V transpose only (rope fused into QKV GEMM epilogue) ----
__global__ __launch_bounds__(256) void k_vt(const short* __restrict__ qkv,
                                            short* __restrict__ vt) {
  __shared__ short tile[128 * 137];
  const int id = blockIdx.x, t = threadIdx.x;
  int s0 = (id & 15) * 128;
  int kvh = (id >> 4) & 3, b = id >> 6;
  const short* src = qkv + (size_t)(b * SEQ) * LDQKV + 2560 + kvh * 128;
#pragma unroll
  for (int rep = 0; rep < 8; ++rep) {
    int lin = rep * 2048 + t * 8;
    int si = lin >> 7, d = lin & 127;
    short8 v = *(const short8*)(src + (size_t)(s0 + si) * LDQKV + d);
#pragma unroll
    for (int j = 0; j < 8; ++j) tile[si * 137 + d + j] = v[j];
  }
  __syncthreads();
  short* dst = vt + (size_t)((b * 4 + kvh) * 128) * SEQ;
#pragma unroll
  for (int rep = 0; rep < 8; ++rep) {
    int lin = rep * 2048 + t * 8;
    int d = lin >> 7, sb = lin & 127;
    short8 o;
#pragma unroll
    for (int j = 0; j < 8; ++j) o[j] = tile[(sb + j) * 137 + d];
    *(short8*)(dst + (size_t)d * SEQ + s0 + sb) = o;
  }
}

// ---------------- flash attention (causal, GQA), 32x32 MFMA ----------------
// R14-proven: 2-buffer dbuf, 64KB LDS -> 2 blocks/CU, __syncthreads/iter.
__global__ __launch_bounds__(256, 2) void k_attn(const short* __restrict__ qkv,
                                                 const short* __restrict__ vt,
                                                 short* __restrict__ outp) {
  __shared__ short Ks[2][64 * 128];
  __shared__ short Vs[2][128 * 64];
  const int t = threadIdx.x, l = t & 63, w = t >> 6;
  const int wr = w >> 1, wk = w & 1;
  const int h = blockIdx.y, b = blockIdx.z;
  const int kvh = h >> 2;
  const int lo5 = l & 31, hi = l >> 5;

  const int kkey = t >> 4, kd8 = t & 15;
  const int vdd = t >> 3, vs8 = t & 7;
  const short* kbase = qkv + (size_t)(b * SEQ) * LDQKV + 2048 + kvh * HD;
  const short* vbase = vt + (size_t)((b * 4 + kvh) * 128) * SEQ;

  auto stageKV = [&](int buf, int it) {
    const int kt = it * 64;
    short* kdst = &Ks[buf][w * 512];
    short* vdst = &Vs[buf][w * 512];
#pragma unroll
    for (int i = 0; i < 4; ++i) {
      int key = i * 16 + kkey;
      int sd = (kd8 ^ (key & 15)) * 8;
      gload_lds16(kbase + (size_t)(kt + key) * LDQKV + sd, kdst + i * 2048);
    }
#pragma unroll
    for (int i = 0; i < 4; ++i) {
      int d = i * 32 + vdd;
      int ss = (vs8 ^ (d & 7)) * 8;
      gload_lds16(vbase + (size_t)d * SEQ + kt + ss, vdst + i * 2048);
    }
  };

  int koff[8], voff[4][2];
#pragma unroll
  for (int s = 0; s < 8; ++s)
    koff[s] = (wk * 32 + lo5) * 128 + (((hi + 2 * s) ^ (l & 15)) * 8);
#pragma unroll
  for (int db = 0; db < 4; ++db)
#pragma unroll
    for (int s = 0; s < 2; ++s)
      voff[db][s] =
          (db * 32 + lo5) * 64 + (((4 * wk + hi + 2 * s) ^ (l & 7)) * 8);
  const int kbloc = wk * 32 + 4 * hi;
  const int qloc = wr * 32 + lo5;

  for (int part = 0; part < 2; ++part) {
    const int qt = part ? (31 - (int)blockIdx.x) : (int)blockIdx.x;
    const int q0 = qt * 64;

    short8 qf[8];
    {
      const short* qrow =
          qkv + (size_t)(b * SEQ + q0 + wr * 32 + lo5) * LDQKV + h * HD;
#pragma unroll
      for (int s = 0; s < 8; ++s)
        qf[s] = *(const short8*)(qrow + s * 16 + hi * 8);
    }

    f32x16 of[4] = {};
    float mrun = 0.f, lsum = 0.f;

    const int nt = qt + 1;
    stageKV(0, 0);
    __syncthreads();

    for (int it = 0; it < nt; ++it) {
      const int buf = it & 1;
      if (it + 1 < nt) stageKV(buf ^ 1, it + 1);
      const short* KsC = Ks[buf];
      const short* VsC = Vs[buf];

      // QK^T: 2 accumulator chains (even/odd s), summed once
      f32x16 sca = {}, scb = {};
      __builtin_amdgcn_s_setprio(1);
#pragma unroll
      for (int s = 0; s < 4; ++s) {
        short8 kf0 = *(const short8*)(KsC + koff[2 * s]);
        short8 kf1 = *(const short8*)(KsC + koff[2 * s + 1]);
        sca = mfma32(kf0, qf[2 * s], sca);
        scb = mfma32(kf1, qf[2 * s + 1], scb);
      }
      __builtin_amdgcn_s_setprio(0);
      f32x16 sc = sca + scb;

      if (it == nt - 1) {
#pragma unroll
        for (int r = 0; r < 16; ++r) {
          const int off = (r & 3) + 8 * (r >> 2);
          if (kbloc + off > qloc) sc[r] = -1e30f;
        }
      }

      float lmax = sc[0];
#pragma unroll
      for (int r = 1; r < 16; ++r) lmax = fmaxf(lmax, sc[r]);
      if (__any(lmax > mrun + 8.f)) {
        float mx = fmaxf(lmax, __shfl_xor(lmax, 32));
        float mm = fmaxf(mrun, mx);
        float rs = fexp2(mrun - mm);
        mrun = mm;
        lsum *= rs;
#pragma unroll
        for (int db = 0; db < 4; ++db)
#pragma unroll
          for (int r = 0; r < 16; ++r) of[db][r] *= rs;
      }

      float p[16];
#pragma unroll
      for (int r = 0; r < 16; ++r) {
        p[r] = fexp2(sc[r] - mrun);
        lsum += p[r];
      }
      unsigned int pk[8];
#pragma unroll
      for (int j = 0; j < 8; ++j) pk[j] = cvt_pk(p[2 * j], p[2 * j + 1]);

      unsigned int s0 = hi ? pk[0] : pk[2];
      unsigned int s1 = hi ? pk[1] : pk[3];
      unsigned int s2 = hi ? pk[4] : pk[6];
      unsigned int s3 = hi ? pk[5] : pk[7];
      unsigned int x0 = __shfl_xor(s0, 32);
      unsigned int x1 = __shfl_xor(s1, 32);
      unsigned int x2 = __shfl_xor(s2, 32);
      unsigned int x3 = __shfl_xor(s3, 32);
      u32x4 b0w, b1w;
      b0w.x = hi ? x0 : pk[0];
      b0w.y = hi ? x1 : pk[1];
      b0w.z = hi ? pk[2] : x0;
      b0w.w = hi ? pk[3] : x1;
      b1w.x = hi ? x2 : pk[4];
      b1w.y = hi ? x3 : pk[5];
      b1w.z = hi ? pk[6] : x2;
      b1w.w = hi ? pk[7] : x3;
      short8 pb[2] = {__builtin_bit_cast(short8, b0w),
                      __builtin_bit_cast(short8, b1w)};

      __builtin_amdgcn_s_setprio(1);
#pragma unroll
      for (int s = 0; s < 2; ++s)
#pragma unroll
        for (int db = 0; db < 4; ++db) {
          short8 vf = *(const short8*)(VsC + voff[db][s]);
          of[db] = mfma32(vf, pb[s], of[db]);
        }
      __builtin_amdgcn_s_setprio(0);
      __syncthreads();
    }

    lsum += __shfl_xor(lsum, 32);
    float* og = (float*)Ks;
    float* sg = (float*)Vs;
    if (wk == 1) {
#pragma unroll
      for (int db = 0; db < 4; ++db)
#pragma unroll
        for (int r4 = 0; r4 < 4; ++r4) {
          int g = db * 4 + r4;
          f32x4 v;
#pragma unroll
          for (int j = 0; j < 4; ++j) v[j] = of[db][r4 * 4 + j];
          *(f32x4*)&og[wr * 4096 + l * 64 + ((g ^ (l & 15)) * 4)] = v;
        }
      sg[wr * 64 + l] = mrun;
      sg[128 + wr * 64 + l] = lsum;
    }
    __syncthreads();
    if (wk == 0) {
      float m1 = sg[wr * 64 + l];
      float l1 = sg[128 + wr * 64 + l];
      float mt = fmaxf(mrun, m1);
      float r0 = fexp2(mrun - mt), r1 = fexp2(m1 - mt);
      float inv = 1.0f / (lsum * r0 + l1 * r1);
      short* ob =
          outp + (size_t)(b * SEQ + q0 + wr * 32 + lo5) * 2048 + h * HD;
#pragma unroll
      for (int db = 0; db < 4; ++db) {
#pragma unroll
        for (int r4 = 0; r4 < 4; ++r4) {
          int g = db * 4 + r4;
          f32x4 o1 = *(const f32x4*)&og[wr * 4096 + l * 64 +
                                        ((g ^ (l & 15)) * 4)];
          u32x2 pko;
          float v0 = (of[db][r4 * 4 + 0] * r0 + o1[0] * r1) * inv;
          float v1 = (of[db][r4 * 4 + 1] * r0 + o1[1] * r1) * inv;
          float v2 = (of[db][r4 * 4 + 2] * r0 + o1[2] * r1) * inv;
          float v3 = (of[db][r4 * 4 + 3] * r0 + o1[3] * r1) * inv;
          pko.x = cvt_pk(v0, v1);
          pko.y = cvt_pk(v2, v3);
          *(u32x2*)(ob + db * 32 + 8 * r4 + 4 * hi) = pko;
        }
      }
    }
    __syncthreads();  // protect merge region before next part's staging
  }
}

extern "C" void kernel_launch(void* const* d_in, const int* in_sizes, int n_in,
                              void* d_out, int out_size, void* d_ws,
                              size_t ws_size, hipStream_t stream) {
  const float* x = (const float*)d_in[0];
  const float* wq = (const float*)d_in[1];
  const float* wk = (const float*)d_in[2];
  const float* wv = (const float*)d_in[3];
  const float* wo = (const float*)d_in[4];
  const float* fc = (const float*)d_in[5];
  const float* fs = (const float*)d_in[6];

  char* ws = (char*)d_ws;
  short* xb = (short*)(ws);                           // [4096][2048] 16MB
  short* wT = (short*)(ws + (16ull << 20));           // [3072][2048] 12MB
  short* woT = (short*)(ws + (28ull << 20));          // [2048][2048] 8MB
  short* qkvb = (short*)(ws + (36ull << 20));         // [4096][3072] 24MB
  short* vtb = (short*)(ws + (16ull << 20));          // alias wT (dead) 4MB
  short* attn = (short*)(ws);                         // alias xb (dead) 16MB

  k_prep<<<6656, 256, 0, stream>>>(x, wq, wk, wv, wo, xb, wT, woT);
  k_gemm256<2, 0, 1><<<192, 512, 0, stream>>>(xb, wT, qkvb, fc, fs,
                                              4096, 3072, 2048);
  k_vt<<<128, 256, 0, stream>>>(qkvb, vtb);
  k_attn<<<dim3(16, 16, 2), 256, 0, stream>>>(qkvb, vtb, attn);
  k_gemm256<1, 1, 0><<<256, 512, 0, stream>>>(attn, woT, d_out, nullptr,
                                              nullptr, 4096, 2048, 2048);
}

// Round 18
// 174.819 us; speedup vs baseline: 1.0497x; 1.0497x over previous
//
#include <hip/hip_runtime.h>
#include <stdint.h>

#define SEQ   2048
#define NB    2
#define LDQKV 3072
#define HD    128
// 1/sqrt(128) * log2(e): QK^T scores land in base-2 domain -> exp2 directly.
#define QSCALE2 (0.08838834764831845f * 1.44269504088896340f)

typedef __attribute__((ext_vector_type(8))) short short8;
typedef __attribute__((ext_vector_type(4))) short short4v;
typedef __attribute__((ext_vector_type(4))) float f32x4;
typedef __attribute__((ext_vector_type(16))) float f32x16;
typedef __attribute__((ext_vector_type(4))) unsigned int u32x4;
typedef __attribute__((ext_vector_type(2))) unsigned int u32x2;
typedef __attribute__((ext_vector_type(8))) __bf16 bf16x8;

__device__ __forceinline__ float bs2f(short s) {
  unsigned int u = ((unsigned int)(unsigned short)s) << 16;
  return __builtin_bit_cast(float, u);
}
__device__ __forceinline__ short f2bs(float f) {
  unsigned int u = __builtin_bit_cast(unsigned int, f);
  u += 0x7fffu + ((u >> 16) & 1u);
  return (short)(u >> 16);
}
__device__ __forceinline__ unsigned int cvt_pk(float lo, float hi) {
  unsigned int r;
  asm("v_cvt_pk_bf16_f32 %0, %1, %2" : "=v"(r) : "v"(lo), "v"(hi));
  return r;
}
// bare v_exp_f32 (2^x): avoids ocml exp2f edge-handling (~15 VALU each)
__device__ __forceinline__ float fexp2(float x) {
  float r;
  asm("v_exp_f32 %0, %1" : "=v"(r) : "v"(x));
  return r;
}
__device__ __forceinline__ f32x4 mfma16(short8 a, short8 b, f32x4 c) {
  return __builtin_amdgcn_mfma_f32_16x16x32_bf16(
      __builtin_bit_cast(bf16x8, a), __builtin_bit_cast(bf16x8, b), c, 0, 0, 0);
}
__device__ __forceinline__ f32x16 mfma32(short8 a, short8 b, f32x16 c) {
  return __builtin_amdgcn_mfma_f32_32x32x16_bf16(
      __builtin_bit_cast(bf16x8, a), __builtin_bit_cast(bf16x8, b), c, 0, 0, 0);
}
__device__ __forceinline__ void gload_lds16(const void* g, void* l) {
  __builtin_amdgcn_global_load_lds(
      (__attribute__((address_space(1))) const void*)(uintptr_t)g,
      (__attribute__((address_space(3))) void*)(unsigned int)(uintptr_t)l,
      16, 0, 0);
}

#define SBAR() asm volatile("s_barrier" ::: "memory")
#define VMC(n) asm volatile("s_waitcnt vmcnt(" #n ")" ::: "memory")

// ---- fused prep: x fp32->bf16 convert + 4 weight transposes, 1D grid ----
__global__ __launch_bounds__(256) void k_prep(const float* __restrict__ x,
                                              const float* __restrict__ wq,
                                              const float* __restrict__ wk,
                                              const float* __restrict__ wv,
                                              const float* __restrict__ wo,
                                              short* __restrict__ xb,
                                              short* __restrict__ wT,
                                              short* __restrict__ woT) {
  __shared__ __align__(16) float tile[64][68];
  const int bid = blockIdx.x, t = threadIdx.x;
  if (bid < 4096) {  // cvt
    int i = bid * 256 + t;
    f32x4 a = *(const f32x4*)(x + (size_t)i * 8);
    f32x4 b = *(const f32x4*)(x + (size_t)i * 8 + 4);
    short8 o;
#pragma unroll
    for (int j = 0; j < 4; ++j) { o[j] = f2bs(a[j]); o[4 + j] = f2bs(b[j]); }
    *(short8*)(xb + (size_t)i * 8) = o;
    return;
  }
  const float* src;
  short* dst;
  int N, id;
  if (bid < 5120)      { id = bid - 4096; src = wq; dst = wT;                        N = 2048; }
  else if (bid < 5376) { id = bid - 5120; src = wk; dst = wT + (size_t)2048 * 2048;  N = 512;  }
  else if (bid < 5632) { id = bid - 5376; src = wv; dst = wT + (size_t)2560 * 2048;  N = 512;  }
  else                 { id = bid - 5632; src = wo; dst = woT;                       N = 2048; }
  const int K = 2048;
  int k0 = (id & 31) * 64, n0 = (id >> 5) * 64;
#pragma unroll
  for (int rep = 0; rep < 4; ++rep) {
    int lin = rep * 1024 + t * 4;
    int kk = lin >> 6, nn = lin & 63;
    f32x4 v = *(const f32x4*)(src + (size_t)(k0 + kk) * N + n0 + nn);
    *(f32x4*)(&tile[kk][nn]) = v;
  }
  __syncthreads();
#pragma unroll
  for (int rep = 0; rep < 4; ++rep) {
    int lin = rep * 1024 + t * 4;
    int nn = lin >> 6, kk = lin & 63;
    short4v o;
#pragma unroll
    for (int j = 0; j < 4; ++j) o[j] = f2bs(tile[kk + j][nn]);
    *(short4v*)(dst + (size_t)(n0 + nn) * K + k0 + kk) = o;
  }
}

// ---- QKV GEMM: 128x384 tile -> 256 blocks = 1/CU (100% coverage) ----
// qkv[4096][3072] = xb[4096][2048] * wT[3072][2048]^T, rope fused.
// 8 waves (2M x 4N): wave = 64 rows x 96 cols; acc 4x6. BK=64.
// Early stage = B (6 loads), late = A (2); boundary VMC(2) forces tile v+1.
__global__ __launch_bounds__(512, 2) void k_gemmQ(const short* __restrict__ A,
                                                  const short* __restrict__ Bt,
                                                  short* __restrict__ Cp,
                                                  const float* __restrict__ fcos,
                                                  const float* __restrict__ fsin) {
  __shared__ short Al[2][128 * 64];
  __shared__ short Bl[2][384 * 64];
  const int t = threadIdx.x, l = t & 63, w = t >> 6;
  const int pm = w >> 2, pn = w & 3;
  const int lrow = l & 15, lg = l >> 4;
  const int K = 2048, NT = 32;

  const int id2 = ((int)blockIdx.x & 7) * 32 + ((int)blockIdx.x >> 3);
  const int m0 = (id2 & 31) * 128, n0 = (id2 >> 5) * 384;

  const int srow = w * 8 + (l >> 3);
  const int sgx = ((l & 7) ^ (srow & 7)) * 8;
  const short* Abase = A + (size_t)(m0 + srow) * K + sgx;
  const short* Bbase = Bt + (size_t)(n0 + srow) * K + sgx;

  f32x4 acc[4][6] = {};
  short8 aFr[4][2], bFr[6][2];

  auto stgA = [&](int d, int tv) {
#pragma unroll
    for (int j = 0; j < 2; ++j)
      gload_lds16(Abase + (size_t)(j * 64) * K + (size_t)tv * 64,
                  &Al[d][j * 4096 + w * 512]);
  };
  auto stgB = [&](int d, int tv) {
#pragma unroll
    for (int j = 0; j < 6; ++j)
      gload_lds16(Bbase + (size_t)(j * 64) * K + (size_t)tv * 64,
                  &Bl[d][j * 4096 + w * 512]);
  };
  auto rdA = [&](int d) {
#pragma unroll
    for (int mi = 0; mi < 4; ++mi) {
      int rl = pm * 64 + mi * 16 + lrow;
#pragma unroll
      for (int kk = 0; kk < 2; ++kk)
        aFr[mi][kk] = *(const short8*)&Al[d][rl * 64 +
                                             (((kk * 4 + lg) ^ (rl & 7)) * 8)];
    }
  };
  auto rdB = [&](int d) {
#pragma unroll
    for (int ni = 0; ni < 6; ++ni) {
      int rl = pn * 96 + ni * 16 + lrow;
#pragma unroll
      for (int kk = 0; kk < 2; ++kk)
        bFr[ni][kk] = *(const short8*)&Bl[d][rl * 64 +
                                             (((kk * 4 + lg) ^ (rl & 7)) * 8)];
    }
  };

  // prologue: tile0 (A+B) staged; late A(1) in flight
  stgA(0, 0);
  stgB(0, 0);
  stgA(1, 1);
  VMC(2);
  SBAR();

  for (int v = 0; v < NT; ++v) {
    const int d = v & 1, d1 = d ^ 1;
    if (v + 1 < NT) stgB(d1, v + 1);  // early: next tile's B
    rdA(d);
    rdB(d);
    __builtin_amdgcn_s_setprio(1);
#pragma unroll
    for (int mi = 0; mi < 4; ++mi)
#pragma unroll
      for (int ni = 0; ni < 3; ++ni)
#pragma unroll
        for (int kk = 0; kk < 2; ++kk)
          acc[mi][ni] = mfma16(aFr[mi][kk], bFr[ni][kk], acc[mi][ni]);
    __builtin_amdgcn_s_setprio(0);
    SBAR();  // all waves' d-slot reads done
    if (v + 2 < NT) stgA(d, v + 2);  // late: tile v+2's A into freed d slots
    __builtin_amdgcn_s_setprio(1);
#pragma unroll
    for (int mi = 0; mi < 4; ++mi)
#pragma unroll
      for (int ni = 3; ni < 6; ++ni)
#pragma unroll
        for (int kk = 0; kk < 2; ++kk)
          acc[mi][ni] = mfma16(aFr[mi][kk], bFr[ni][kk], acc[mi][ni]);
    __builtin_amdgcn_s_setprio(0);
    if (v + 2 < NT) { VMC(2); } else { VMC(0); }
    SBAR();
  }

  // epilogue: rope on q ([0,2048), *QSCALE2) and k ([2048,2560)); store bf16
  const bool ev = ((lrow & 1) == 0);
#pragma unroll
  for (int mi = 0; mi < 4; ++mi) {
    const int row = m0 + pm * 64 + mi * 16 + lg * 4;
#pragma unroll
    for (int ni = 0; ni < 6; ++ni) {
      const int colb = n0 + pn * 96 + ni * 16;  // store-uniform
      const int col = colb + lrow;
      f32x4 vv = acc[mi][ni];
      if (colb < 2560) {
        const float qs = (colb < 2048) ? QSCALE2 : 1.0f;
        const int pi = ((pn * 96 + ni * 16 + lrow) & 127) >> 1;
#pragma unroll
        for (int v2 = 0; v2 < 4; ++v2) {
          float c = fcos[(size_t)(row + v2) * 64 + pi] * qs;
          float s = fsin[(size_t)(row + v2) * 64 + pi] * qs;
          float xx = vv[v2];
          float xp = __shfl_xor(xx, 1);
          vv[v2] = ev ? (xx * c - xp * s) : (xp * s + xx * c);
        }
      }
#pragma unroll
      for (int v2 = 0; v2 < 4; ++v2)
        Cp[(size_t)(row + v2) * LDQKV + col] = f2bs(vv[v2]);
    }
  }
}

// ------- outproj GEMM 256x128 tile (NH=1), 2-barrier read-ahead (proven) ----
template <int NH, int FP32OUT, int ROPE>
__global__ __launch_bounds__(512, 2) void k_gemm256(const short* __restrict__ A,
                                                    const short* __restrict__ Bt,
                                                    void* __restrict__ Cp,
                                                    const float* __restrict__ fcos,
                                                    const float* __restrict__ fsin,
                                                    int M, int N, int K) {
  __shared__ short Al[2][2][128 * 64];
  __shared__ short Bl[2][NH][128 * 64];
  const int t = threadIdx.x, l = t & 63, w = t >> 6;
  const int pm = w >> 2, pn = w & 3;
  const int lrow = l & 15, lg = l >> 4;
  const int NT = K >> 6;

  const int nbm = M >> 8;
  const int per = gridDim.x >> 3;
  const int id2 = (blockIdx.x & 7) * per + (blockIdx.x >> 3);
  const int m0 = (id2 % nbm) * 256, n0 = (id2 / nbm) * (NH * 128);

  const int srow = w * 8 + (l >> 3);
  const int sgx = ((l & 7) ^ (srow & 7)) * 8;
  const short* Abase = A + (size_t)(m0 + srow) * K + sgx;
  const short* Bbase = Bt + (size_t)(n0 + srow) * K + sgx;

  f32x4 acc[8][NH * 2] = {};
  short8 aFr0[4][2], aFr1[4][2], bFr[NH][2][2];

  auto stgA = [&](int d, int h, int tv) {
    const short* g = Abase + (size_t)(h * 128) * K + (size_t)tv * 64;
    gload_lds16(g, &Al[d][h][w * 512]);
    gload_lds16(g + (size_t)64 * K, &Al[d][h][w * 512 + 4096]);
  };
  auto stgB = [&](int d, int h, int tv) {
    const short* g = Bbase + (size_t)(h * 128) * K + (size_t)tv * 64;
    gload_lds16(g, &Bl[d][h][w * 512]);
    gload_lds16(g + (size_t)64 * K, &Bl[d][h][w * 512 + 4096]);
  };
  auto rdA = [&](int d, int Mh, short8 (*dst)[2]) {
#pragma unroll
    for (int mi = 0; mi < 4; ++mi) {
      int rl = pm * 64 + mi * 16 + lrow;
#pragma unroll
      for (int kk = 0; kk < 2; ++kk)
        dst[mi][kk] = *(const short8*)&Al[d][Mh][rl * 64 +
                                                 (((kk * 4 + lg) ^ (rl & 7)) * 8)];
    }
  };
  auto rdB = [&](int d) {
#pragma unroll
    for (int h = 0; h < NH; ++h)
#pragma unroll
      for (int ni = 0; ni < 2; ++ni) {
        int rl = pn * 32 + ni * 16 + lrow;
#pragma unroll
        for (int kk = 0; kk < 2; ++kk)
          bFr[h][ni][kk] =
              *(const short8*)&Bl[d][h][rl * 64 +
                                        (((kk * 4 + lg) ^ (rl & 7)) * 8)];
      }
  };

#define MMH(Mh, FR)                                                          \
  do {                                                                       \
    __builtin_amdgcn_s_setprio(1);                                           \
    _Pragma("unroll") for (int h = 0; h < NH; ++h)                           \
        _Pragma("unroll") for (int mi = 0; mi < 4; ++mi)                     \
            _Pragma("unroll") for (int ni = 0; ni < 2; ++ni)                 \
                _Pragma("unroll") for (int kk = 0; kk < 2; ++kk)             \
                    acc[(Mh)*4 + mi][h * 2 + ni] =                           \
                        mfma16(FR[mi][kk], bFr[h][ni][kk],                   \
                               acc[(Mh)*4 + mi][h * 2 + ni]);                \
    __builtin_amdgcn_s_setprio(0);                                           \
  } while (0)

  stgA(0, 0, 0);
  for (int h = 0; h < NH; ++h) stgB(0, h, 0);
  stgA(0, 1, 0);
  stgA(1, 0, 1);
  if (NH == 2) stgB(1, 1, 1);
  if (NH == 2) { VMC(4); } else { VMC(2); }
  SBAR();

  for (int v = 0; v < NT; ++v) {
    const int d = v & 1, d1 = d ^ 1;
    rdA(d, 0, aFr0);
    rdB(d);
    rdA(d, 1, aFr1);
    if (v + 1 < NT) { stgB(d1, 0, v + 1); stgA(d1, 1, v + 1); }
    MMH(0, aFr0);
    SBAR();
    if (v + 2 < NT) {
      stgA(d, 0, v + 2);
      if (NH == 2) stgB(d, 1, v + 2);
    }
    MMH(1, aFr1);
    if (v + 2 < NT) {
      if (NH == 2) { VMC(4); } else { VMC(2); }
    } else {
      VMC(0);
    }
    SBAR();
  }
#undef MMH

#pragma unroll
  for (int Mh = 0; Mh < 2; ++Mh)
#pragma unroll
    for (int mi = 0; mi < 4; ++mi) {
      const int row = m0 + Mh * 128 + pm * 64 + mi * 16 + lg * 4;
#pragma unroll
      for (int h = 0; h < NH; ++h)
#pragma unroll
        for (int ni = 0; ni < 2; ++ni) {
          int col = n0 + h * 128 + pn * 32 + ni * 16 + lrow;
          f32x4 vv = acc[Mh * 4 + mi][h * 2 + ni];
#pragma unroll
          for (int v2 = 0; v2 < 4; ++v2) {
            if constexpr (FP32OUT)
              ((float*)Cp)[(size_t)(row + v2) * N + col] = vv[v2];
            else
              ((short*)Cp)[(size_t)(row + v2) * N + col] = f2bs(vv[v2]);
          }
        }
    }
}

// ---- V transpose only (rope fused into QKV GEMM epilogue) ----
__global__ __launch_bounds__(256) void k_vt(const short* __restrict__ qkv,
                                            short* __restrict__ vt) {
  __shared__ short tile[128 * 137];
  const int id = blockIdx.x, t = threadIdx.x;
  int s0 = (id & 15) * 128;
  int kvh = (id >> 4) & 3, b = id >> 6;
  const short* src = qkv + (size_t)(b * SEQ) * LDQKV + 2560 + kvh * 128;
#pragma unroll
  for (int rep = 0; rep < 8; ++rep) {
    int lin = rep * 2048 + t * 8;
    int si = lin >> 7, d = lin & 127;
    short8 v = *(const short8*)(src + (size_t)(s0 + si) * LDQKV + d);
#pragma unroll
    for (int j = 0; j < 8; ++j) tile[si * 137 + d + j] = v[j];
  }
  __syncthreads();
  short* dst = vt + (size_t)((b * 4 + kvh) * 128) * SEQ;
#pragma unroll
  for (int rep = 0; rep < 8; ++rep) {
    int lin = rep * 2048 + t * 8;
    int d = lin >> 7, sb = lin & 127;
    short8 o;
#pragma unroll
    for (int j = 0; j < 8; ++j) o[j] = tile[(sb + j) * 137 + d];
    *(short8*)(dst + (size_t)d * SEQ + s0 + sb) = o;
  }
}

// ---------------- flash attention (causal, GQA), 32x32 MFMA ----------------
// R14-proven: 2-buffer dbuf, 64KB LDS -> 2 blocks/CU, __syncthreads/iter.
__global__ __launch_bounds__(256, 2) void k_attn(const short* __restrict__ qkv,
                                                 const short* __restrict__ vt,
                                                 short* __restrict__ outp) {
  __shared__ short Ks[2][64 * 128];
  __shared__ short Vs[2][128 * 64];
  const int t = threadIdx.x, l = t & 63, w = t >> 6;
  const int wr = w >> 1, wk = w & 1;
  const int h = blockIdx.y, b = blockIdx.z;
  const int kvh = h >> 2;
  const int lo5 = l & 31, hi = l >> 5;

  const int kkey = t >> 4, kd8 = t & 15;
  const int vdd = t >> 3, vs8 = t & 7;
  const short* kbase = qkv + (size_t)(b * SEQ) * LDQKV + 2048 + kvh * HD;
  const short* vbase = vt + (size_t)((b * 4 + kvh) * 128) * SEQ;

  auto stageKV = [&](int buf, int it) {
    const int kt = it * 64;
    short* kdst = &Ks[buf][w * 512];
    short* vdst = &Vs[buf][w * 512];
#pragma unroll
    for (int i = 0; i < 4; ++i) {
      int key = i * 16 + kkey;
      int sd = (kd8 ^ (key & 15)) * 8;
      gload_lds16(kbase + (size_t)(kt + key) * LDQKV + sd, kdst + i * 2048);
    }
#pragma unroll
    for (int i = 0; i < 4; ++i) {
      int d = i * 32 + vdd;
      int ss = (vs8 ^ (d & 7)) * 8;
      gload_lds16(vbase + (size_t)d * SEQ + kt + ss, vdst + i * 2048);
    }
  };

  int koff[8], voff[4][2];
#pragma unroll
  for (int s = 0; s < 8; ++s)
    koff[s] = (wk * 32 + lo5) * 128 + (((hi + 2 * s) ^ (l & 15)) * 8);
#pragma unroll
  for (int db = 0; db < 4; ++db)
#pragma unroll
    for (int s = 0; s < 2; ++s)
      voff[db][s] =
          (db * 32 + lo5) * 64 + (((4 * wk + hi + 2 * s) ^ (l & 7)) * 8);
  const int kbloc = wk * 32 + 4 * hi;
  const int qloc = wr * 32 + lo5;

  for (int part = 0; part < 2; ++part) {
    const int qt = part ? (31 - (int)blockIdx.x) : (int)blockIdx.x;
    const int q0 = qt * 64;

    short8 qf[8];
    {
      const short* qrow =
          qkv + (size_t)(b * SEQ + q0 + wr * 32 + lo5) * LDQKV + h * HD;
#pragma unroll
      for (int s = 0; s < 8; ++s)
        qf[s] = *(const short8*)(qrow + s * 16 + hi * 8);
    }

    f32x16 of[4] = {};
    float mrun = 0.f, lsum = 0.f;

    const int nt = qt + 1;
    stageKV(0, 0);
    __syncthreads();

    for (int it = 0; it < nt; ++it) {
      const int buf = it & 1;
      if (it + 1 < nt) stageKV(buf ^ 1, it + 1);
      const short* KsC = Ks[buf];
      const short* VsC = Vs[buf];

      f32x16 sca = {}, scb = {};
      __builtin_amdgcn_s_setprio(1);
#pragma unroll
      for (int s = 0; s < 4; ++s) {
        short8 kf0 = *(const short8*)(KsC + koff[2 * s]);
        short8 kf1 = *(const short8*)(KsC + koff[2 * s + 1]);
        sca = mfma32(kf0, qf[2 * s], sca);
        scb = mfma32(kf1, qf[2 * s + 1], scb);
      }
      __builtin_amdgcn_s_setprio(0);
      f32x16 sc = sca + scb;

      if (it == nt - 1) {
#pragma unroll
        for (int r = 0; r < 16; ++r) {
          const int off = (r & 3) + 8 * (r >> 2);
          if (kbloc + off > qloc) sc[r] = -1e30f;
        }
      }

      float lmax = sc[0];
#pragma unroll
      for (int r = 1; r < 16; ++r) lmax = fmaxf(lmax, sc[r]);
      if (__any(lmax > mrun + 8.f)) {
        float mx = fmaxf(lmax, __shfl_xor(lmax, 32));
        float mm = fmaxf(mrun, mx);
        float rs = fexp2(mrun - mm);
        mrun = mm;
        lsum *= rs;
#pragma unroll
        for (int db = 0; db < 4; ++db)
#pragma unroll
          for (int r = 0; r < 16; ++r) of[db][r] *= rs;
      }

      float p[16];
#pragma unroll
      for (int r = 0; r < 16; ++r) {
        p[r] = fexp2(sc[r] - mrun);
        lsum += p[r];
      }
      unsigned int pk[8];
#pragma unroll
      for (int j = 0; j < 8; ++j) pk[j] = cvt_pk(p[2 * j], p[2 * j + 1]);

      unsigned int s0 = hi ? pk[0] : pk[2];
      unsigned int s1 = hi ? pk[1] : pk[3];
      unsigned int s2 = hi ? pk[4] : pk[6];
      unsigned int s3 = hi ? pk[5] : pk[7];
      unsigned int x0 = __shfl_xor(s0, 32);
      unsigned int x1 = __shfl_xor(s1, 32);
      unsigned int x2 = __shfl_xor(s2, 32);
      unsigned int x3 = __shfl_xor(s3, 32);
      u32x4 b0w, b1w;
      b0w.x = hi ? x0 : pk[0];
      b0w.y = hi ? x1 : pk[1];
      b0w.z = hi ? pk[2] : x0;
      b0w.w = hi ? pk[3] : x1;
      b1w.x = hi ? x2 : pk[4];
      b1w.y = hi ? x3 : pk[5];
      b1w.z = hi ? pk[6] : x2;
      b1w.w = hi ? pk[7] : x3;
      short8 pb[2] = {__builtin_bit_cast(short8, b0w),
                      __builtin_bit_cast(short8, b1w)};

      __builtin_amdgcn_s_setprio(1);
#pragma unroll
      for (int s = 0; s < 2; ++s)
#pragma unroll
        for (int db = 0; db < 4; ++db) {
          short8 vf = *(const short8*)(VsC + voff[db][s]);
          of[db] = mfma32(vf, pb[s], of[db]);
        }
      __builtin_amdgcn_s_setprio(0);
      __syncthreads();
    }

    lsum += __shfl_xor(lsum, 32);
    float* og = (float*)Ks;
    float* sg = (float*)Vs;
    if (wk == 1) {
#pragma unroll
      for (int db = 0; db < 4; ++db)
#pragma unroll
        for (int r4 = 0; r4 < 4; ++r4) {
          int g = db * 4 + r4;
          f32x4 v;
#pragma unroll
          for (int j = 0; j < 4; ++j) v[j] = of[db][r4 * 4 + j];
          *(f32x4*)&og[wr * 4096 + l * 64 + ((g ^ (l & 15)) * 4)] = v;
        }
      sg[wr * 64 + l] = mrun;
      sg[128 + wr * 64 + l] = lsum;
    }
    __syncthreads();
    if (wk == 0) {
      float m1 = sg[wr * 64 + l];
      float l1 = sg[128 + wr * 64 + l];
      float mt = fmaxf(mrun, m1);
      float r0 = fexp2(mrun - mt), r1 = fexp2(m1 - mt);
      float inv = 1.0f / (lsum * r0 + l1 * r1);
      short* ob =
          outp + (size_t)(b * SEQ + q0 + wr * 32 + lo5) * 2048 + h * HD;
#pragma unroll
      for (int db = 0; db < 4; ++db) {
#pragma unroll
        for (int r4 = 0; r4 < 4; ++r4) {
          int g = db * 4 + r4;
          f32x4 o1 = *(const f32x4*)&og[wr * 4096 + l * 64 +
                                        ((g ^ (l & 15)) * 4)];
          u32x2 pko;
          float v0 = (of[db][r4 * 4 + 0] * r0 + o1[0] * r1) * inv;
          float v1 = (of[db][r4 * 4 + 1] * r0 + o1[1] * r1) * inv;
          float v2 = (of[db][r4 * 4 + 2] * r0 + o1[2] * r1) * inv;
          float v3 = (of[db][r4 * 4 + 3] * r0 + o1[3] * r1) * inv;
          pko.x = cvt_pk(v0, v1);
          pko.y = cvt_pk(v2, v3);
          *(u32x2*)(ob + db * 32 + 8 * r4 + 4 * hi) = pko;
        }
      }
    }
    __syncthreads();
  }
}

extern "C" void kernel_launch(void* const* d_in, const int* in_sizes, int n_in,
                              void* d_out, int out_size, void* d_ws,
                              size_t ws_size, hipStream_t stream) {
  const float* x = (const float*)d_in[0];
  const float* wq = (const float*)d_in[1];
  const float* wk = (const float*)d_in[2];
  const float* wv = (const float*)d_in[3];
  const float* wo = (const float*)d_in[4];
  const float* fc = (const float*)d_in[5];
  const float* fs = (const float*)d_in[6];

  char* ws = (char*)d_ws;
  short* xb = (short*)(ws);                           // [4096][2048] 16MB
  short* wT = (short*)(ws + (16ull << 20));           // [3072][2048] 12MB
  short* woT = (short*)(ws + (28ull << 20));          // [2048][2048] 8MB
  short* qkvb = (short*)(ws + (36ull << 20));         // [4096][3072] 24MB
  short* vtb = (short*)(ws + (16ull << 20));          // alias wT (dead) 4MB
  short* attn = (short*)(ws);                         // alias xb (dead) 16MB

  k_prep<<<6656, 256, 0, stream>>>(x, wq, wk, wv, wo, xb, wT, woT);
  k_gemmQ<<<256, 512, 0, stream>>>(xb, wT, qkvb, fc, fs);
  k_vt<<<128, 256, 0, stream>>>(qkvb, vtb);
  k_attn<<<dim3(16, 16, 2), 256, 0, stream>>>(qkvb, vtb, attn);
  k_gemm256<1, 1, 0><<<256, 512, 0, stream>>>(attn, woT, d_out, nullptr,
                                              nullptr, 4096, 2048, 2048);
}

// Round 19
// 174.793 us; speedup vs baseline: 1.0498x; 1.0001x over previous
//
#include <hip/hip_runtime.h>
#include <stdint.h>

#define SEQ   2048
#define NB    2
#define LDQKV 3072
#define HD    128
// 1/sqrt(128) * log2(e): QK^T scores land in base-2 domain -> exp2 directly.
#define QSCALE2 (0.08838834764831845f * 1.44269504088896340f)

typedef __attribute__((ext_vector_type(8))) short short8;
typedef __attribute__((ext_vector_type(4))) short short4v;
typedef __attribute__((ext_vector_type(4))) float f32x4;
typedef __attribute__((ext_vector_type(16))) float f32x16;
typedef __attribute__((ext_vector_type(4))) unsigned int u32x4;
typedef __attribute__((ext_vector_type(2))) unsigned int u32x2;
typedef __attribute__((ext_vector_type(8))) __bf16 bf16x8;

__device__ __forceinline__ float bs2f(short s) {
  unsigned int u = ((unsigned int)(unsigned short)s) << 16;
  return __builtin_bit_cast(float, u);
}
__device__ __forceinline__ short f2bs(float f) {
  unsigned int u = __builtin_bit_cast(unsigned int, f);
  u += 0x7fffu + ((u >> 16) & 1u);
  return (short)(u >> 16);
}
__device__ __forceinline__ unsigned int cvt_pk(float lo, float hi) {
  unsigned int r;
  asm("v_cvt_pk_bf16_f32 %0, %1, %2" : "=v"(r) : "v"(lo), "v"(hi));
  return r;
}
// bare v_exp_f32 (2^x): avoids ocml exp2f edge-handling (~15 VALU each)
__device__ __forceinline__ float fexp2(float x) {
  float r;
  asm("v_exp_f32 %0, %1" : "=v"(r) : "v"(x));
  return r;
}
__device__ __forceinline__ f32x4 mfma16(short8 a, short8 b, f32x4 c) {
  return __builtin_amdgcn_mfma_f32_16x16x32_bf16(
      __builtin_bit_cast(bf16x8, a), __builtin_bit_cast(bf16x8, b), c, 0, 0, 0);
}
__device__ __forceinline__ f32x16 mfma32(short8 a, short8 b, f32x16 c) {
  return __builtin_amdgcn_mfma_f32_32x32x16_bf16(
      __builtin_bit_cast(bf16x8, a), __builtin_bit_cast(bf16x8, b), c, 0, 0, 0);
}
__device__ __forceinline__ void gload_lds16(const void* g, void* l) {
  __builtin_amdgcn_global_load_lds(
      (__attribute__((address_space(1))) const void*)(uintptr_t)g,
      (__attribute__((address_space(3))) void*)(unsigned int)(uintptr_t)l,
      16, 0, 0);
}

#define SBAR() asm volatile("s_barrier" ::: "memory")
#define VMC(n) asm volatile("s_waitcnt vmcnt(" #n ")" ::: "memory")

// ---- fused prep: x fp32->bf16 convert + 4 weight transposes, 1D grid ----
__global__ __launch_bounds__(256) void k_prep(const float* __restrict__ x,
                                              const float* __restrict__ wq,
                                              const float* __restrict__ wk,
                                              const float* __restrict__ wv,
                                              const float* __restrict__ wo,
                                              short* __restrict__ xb,
                                              short* __restrict__ wT,
                                              short* __restrict__ woT) {
  __shared__ __align__(16) float tile[64][68];
  const int bid = blockIdx.x, t = threadIdx.x;
  if (bid < 4096) {  // cvt
    int i = bid * 256 + t;
    f32x4 a = *(const f32x4*)(x + (size_t)i * 8);
    f32x4 b = *(const f32x4*)(x + (size_t)i * 8 + 4);
    short8 o;
#pragma unroll
    for (int j = 0; j < 4; ++j) { o[j] = f2bs(a[j]); o[4 + j] = f2bs(b[j]); }
    *(short8*)(xb + (size_t)i * 8) = o;
    return;
  }
  const float* src;
  short* dst;
  int N, id;
  if (bid < 5120)      { id = bid - 4096; src = wq; dst = wT;                        N = 2048; }
  else if (bid < 5376) { id = bid - 5120; src = wk; dst = wT + (size_t)2048 * 2048;  N = 512;  }
  else if (bid < 5632) { id = bid - 5376; src = wv; dst = wT + (size_t)2560 * 2048;  N = 512;  }
  else                 { id = bid - 5632; src = wo; dst = woT;                       N = 2048; }
  const int K = 2048;
  int k0 = (id & 31) * 64, n0 = (id >> 5) * 64;
#pragma unroll
  for (int rep = 0; rep < 4; ++rep) {
    int lin = rep * 1024 + t * 4;
    int kk = lin >> 6, nn = lin & 63;
    f32x4 v = *(const f32x4*)(src + (size_t)(k0 + kk) * N + n0 + nn);
    *(f32x4*)(&tile[kk][nn]) = v;
  }
  __syncthreads();
#pragma unroll
  for (int rep = 0; rep < 4; ++rep) {
    int lin = rep * 1024 + t * 4;
    int nn = lin >> 6, kk = lin & 63;
    short4v o;
#pragma unroll
    for (int j = 0; j < 4; ++j) o[j] = f2bs(tile[kk + j][nn]);
    *(short4v*)(dst + (size_t)(n0 + nn) * K + k0 + kk) = o;
  }
}

// ---- QKV GEMM: 128x384 tile -> 256 blocks = 1/CU (100% coverage) ----
__global__ __launch_bounds__(512, 2) void k_gemmQ(const short* __restrict__ A,
                                                  const short* __restrict__ Bt,
                                                  short* __restrict__ Cp,
                                                  const float* __restrict__ fcos,
                                                  const float* __restrict__ fsin) {
  __shared__ short Al[2][128 * 64];
  __shared__ short Bl[2][384 * 64];
  const int t = threadIdx.x, l = t & 63, w = t >> 6;
  const int pm = w >> 2, pn = w & 3;
  const int lrow = l & 15, lg = l >> 4;
  const int K = 2048, NT = 32;

  const int id2 = ((int)blockIdx.x & 7) * 32 + ((int)blockIdx.x >> 3);
  const int m0 = (id2 & 31) * 128, n0 = (id2 >> 5) * 384;

  const int srow = w * 8 + (l >> 3);
  const int sgx = ((l & 7) ^ (srow & 7)) * 8;
  const short* Abase = A + (size_t)(m0 + srow) * K + sgx;
  const short* Bbase = Bt + (size_t)(n0 + srow) * K + sgx;

  f32x4 acc[4][6] = {};
  short8 aFr[4][2], bFr[6][2];

  auto stgA = [&](int d, int tv) {
#pragma unroll
    for (int j = 0; j < 2; ++j)
      gload_lds16(Abase + (size_t)(j * 64) * K + (size_t)tv * 64,
                  &Al[d][j * 4096 + w * 512]);
  };
  auto stgB = [&](int d, int tv) {
#pragma unroll
    for (int j = 0; j < 6; ++j)
      gload_lds16(Bbase + (size_t)(j * 64) * K + (size_t)tv * 64,
                  &Bl[d][j * 4096 + w * 512]);
  };
  auto rdA = [&](int d) {
#pragma unroll
    for (int mi = 0; mi < 4; ++mi) {
      int rl = pm * 64 + mi * 16 + lrow;
#pragma unroll
      for (int kk = 0; kk < 2; ++kk)
        aFr[mi][kk] = *(const short8*)&Al[d][rl * 64 +
                                             (((kk * 4 + lg) ^ (rl & 7)) * 8)];
    }
  };
  auto rdB = [&](int d) {
#pragma unroll
    for (int ni = 0; ni < 6; ++ni) {
      int rl = pn * 96 + ni * 16 + lrow;
#pragma unroll
      for (int kk = 0; kk < 2; ++kk)
        bFr[ni][kk] = *(const short8*)&Bl[d][rl * 64 +
                                             (((kk * 4 + lg) ^ (rl & 7)) * 8)];
    }
  };

  // prologue: tile0 (A+B) staged; late A(1) in flight
  stgA(0, 0);
  stgB(0, 0);
  stgA(1, 1);
  VMC(2);
  SBAR();

  for (int v = 0; v < NT; ++v) {
    const int d = v & 1, d1 = d ^ 1;
    if (v + 1 < NT) stgB(d1, v + 1);  // early: next tile's B
    rdA(d);
    rdB(d);
    __builtin_amdgcn_s_setprio(1);
#pragma unroll
    for (int mi = 0; mi < 4; ++mi)
#pragma unroll
      for (int ni = 0; ni < 3; ++ni)
#pragma unroll
        for (int kk = 0; kk < 2; ++kk)
          acc[mi][ni] = mfma16(aFr[mi][kk], bFr[ni][kk], acc[mi][ni]);
    __builtin_amdgcn_s_setprio(0);
    SBAR();  // all waves' d-slot reads done
    if (v + 2 < NT) stgA(d, v + 2);  // late: tile v+2's A into freed d slots
    __builtin_amdgcn_s_setprio(1);
#pragma unroll
    for (int mi = 0; mi < 4; ++mi)
#pragma unroll
      for (int ni = 3; ni < 6; ++ni)
#pragma unroll
        for (int kk = 0; kk < 2; ++kk)
          acc[mi][ni] = mfma16(aFr[mi][kk], bFr[ni][kk], acc[mi][ni]);
    __builtin_amdgcn_s_setprio(0);
    if (v + 2 < NT) { VMC(2); } else { VMC(0); }
    SBAR();
  }

  // epilogue: rope on q ([0,2048), *QSCALE2) and k ([2048,2560)); store bf16
  const bool ev = ((lrow & 1) == 0);
#pragma unroll
  for (int mi = 0; mi < 4; ++mi) {
    const int row = m0 + pm * 64 + mi * 16 + lg * 4;
#pragma unroll
    for (int ni = 0; ni < 6; ++ni) {
      const int colb = n0 + pn * 96 + ni * 16;  // store-uniform
      const int col = colb + lrow;
      f32x4 vv = acc[mi][ni];
      if (colb < 2560) {
        const float qs = (colb < 2048) ? QSCALE2 : 1.0f;
        const int pi = ((pn * 96 + ni * 16 + lrow) & 127) >> 1;
#pragma unroll
        for (int v2 = 0; v2 < 4; ++v2) {
          float c = fcos[(size_t)(row + v2) * 64 + pi] * qs;
          float s = fsin[(size_t)(row + v2) * 64 + pi] * qs;
          float xx = vv[v2];
          float xp = __shfl_xor(xx, 1);
          vv[v2] = ev ? (xx * c - xp * s) : (xp * s + xx * c);
        }
      }
#pragma unroll
      for (int v2 = 0; v2 < 4; ++v2)
        Cp[(size_t)(row + v2) * LDQKV + col] = f2bs(vv[v2]);
    }
  }
}

// ------- outproj GEMM 256x128 tile (NH=1), 2-barrier read-ahead (proven) ----
template <int NH, int FP32OUT, int ROPE>
__global__ __launch_bounds__(512, 2) void k_gemm256(const short* __restrict__ A,
                                                    const short* __restrict__ Bt,
                                                    void* __restrict__ Cp,
                                                    const float* __restrict__ fcos,
                                                    const float* __restrict__ fsin,
                                                    int M, int N, int K) {
  __shared__ short Al[2][2][128 * 64];
  __shared__ short Bl[2][NH][128 * 64];
  const int t = threadIdx.x, l = t & 63, w = t >> 6;
  const int pm = w >> 2, pn = w & 3;
  const int lrow = l & 15, lg = l >> 4;
  const int NT = K >> 6;

  const int nbm = M >> 8;
  const int per = gridDim.x >> 3;
  const int id2 = (blockIdx.x & 7) * per + (blockIdx.x >> 3);
  const int m0 = (id2 % nbm) * 256, n0 = (id2 / nbm) * (NH * 128);

  const int srow = w * 8 + (l >> 3);
  const int sgx = ((l & 7) ^ (srow & 7)) * 8;
  const short* Abase = A + (size_t)(m0 + srow) * K + sgx;
  const short* Bbase = Bt + (size_t)(n0 + srow) * K + sgx;

  f32x4 acc[8][NH * 2] = {};
  short8 aFr0[4][2], aFr1[4][2], bFr[NH][2][2];

  auto stgA = [&](int d, int h, int tv) {
    const short* g = Abase + (size_t)(h * 128) * K + (size_t)tv * 64;
    gload_lds16(g, &Al[d][h][w * 512]);
    gload_lds16(g + (size_t)64 * K, &Al[d][h][w * 512 + 4096]);
  };
  auto stgB = [&](int d, int h, int tv) {
    const short* g = Bbase + (size_t)(h * 128) * K + (size_t)tv * 64;
    gload_lds16(g, &Bl[d][h][w * 512]);
    gload_lds16(g + (size_t)64 * K, &Bl[d][h][w * 512 + 4096]);
  };
  auto rdA = [&](int d, int Mh, short8 (*dst)[2]) {
#pragma unroll
    for (int mi = 0; mi < 4; ++mi) {
      int rl = pm * 64 + mi * 16 + lrow;
#pragma unroll
      for (int kk = 0; kk < 2; ++kk)
        dst[mi][kk] = *(const short8*)&Al[d][Mh][rl * 64 +
                                                 (((kk * 4 + lg) ^ (rl & 7)) * 8)];
    }
  };
  auto rdB = [&](int d) {
#pragma unroll
    for (int h = 0; h < NH; ++h)
#pragma unroll
      for (int ni = 0; ni < 2; ++ni) {
        int rl = pn * 32 + ni * 16 + lrow;
#pragma unroll
        for (int kk = 0; kk < 2; ++kk)
          bFr[h][ni][kk] =
              *(const short8*)&Bl[d][h][rl * 64 +
                                        (((kk * 4 + lg) ^ (rl & 7)) * 8)];
      }
  };

#define MMH(Mh, FR)                                                          \
  do {                                                                       \
    __builtin_amdgcn_s_setprio(1);                                           \
    _Pragma("unroll") for (int h = 0; h < NH; ++h)                           \
        _Pragma("unroll") for (int mi = 0; mi < 4; ++mi)                     \
            _Pragma("unroll") for (int ni = 0; ni < 2; ++ni)                 \
                _Pragma("unroll") for (int kk = 0; kk < 2; ++kk)             \
                    acc[(Mh)*4 + mi][h * 2 + ni] =                           \
                        mfma16(FR[mi][kk], bFr[h][ni][kk],                   \
                               acc[(Mh)*4 + mi][h * 2 + ni]);                \
    __builtin_amdgcn_s_setprio(0);                                           \
  } while (0)

  stgA(0, 0, 0);
  for (int h = 0; h < NH; ++h) stgB(0, h, 0);
  stgA(0, 1, 0);
  stgA(1, 0, 1);
  if (NH == 2) stgB(1, 1, 1);
  if (NH == 2) { VMC(4); } else { VMC(2); }
  SBAR();

  for (int v = 0; v < NT; ++v) {
    const int d = v & 1, d1 = d ^ 1;
    rdA(d, 0, aFr0);
    rdB(d);
    rdA(d, 1, aFr1);
    if (v + 1 < NT) { stgB(d1, 0, v + 1); stgA(d1, 1, v + 1); }
    MMH(0, aFr0);
    SBAR();
    if (v + 2 < NT) {
      stgA(d, 0, v + 2);
      if (NH == 2) stgB(d, 1, v + 2);
    }
    MMH(1, aFr1);
    if (v + 2 < NT) {
      if (NH == 2) { VMC(4); } else { VMC(2); }
    } else {
      VMC(0);
    }
    SBAR();
  }
#undef MMH

#pragma unroll
  for (int Mh = 0; Mh < 2; ++Mh)
#pragma unroll
    for (int mi = 0; mi < 4; ++mi) {
      const int row = m0 + Mh * 128 + pm * 64 + mi * 16 + lg * 4;
#pragma unroll
      for (int h = 0; h < NH; ++h)
#pragma unroll
        for (int ni = 0; ni < 2; ++ni) {
          int col = n0 + h * 128 + pn * 32 + ni * 16 + lrow;
          f32x4 vv = acc[Mh * 4 + mi][h * 2 + ni];
#pragma unroll
          for (int v2 = 0; v2 < 4; ++v2) {
            if constexpr (FP32OUT)
              ((float*)Cp)[(size_t)(row + v2) * N + col] = vv[v2];
            else
              ((short*)Cp)[(size_t)(row + v2) * N + col] = f2bs(vv[v2]);
          }
        }
    }
}

// ---- V transpose only (rope fused into QKV GEMM epilogue) ----
__global__ __launch_bounds__(256) void k_vt(const short* __restrict__ qkv,
                                            short* __restrict__ vt) {
  __shared__ short tile[128 * 137];
  const int id = blockIdx.x, t = threadIdx.x;
  int s0 = (id & 15) * 128;
  int kvh = (id >> 4) & 3, b = id >> 6;
  const short* src = qkv + (size_t)(b * SEQ) * LDQKV + 2560 + kvh * 128;
#pragma unroll
  for (int rep = 0; rep < 8; ++rep) {
    int lin = rep * 2048 + t * 8;
    int si = lin >> 7, d = lin & 127;
    short8 v = *(const short8*)(src + (size_t)(s0 + si) * LDQKV + d);
#pragma unroll
    for (int j = 0; j < 8; ++j) tile[si * 137 + d + j] = v[j];
  }
  __syncthreads();
  short* dst = vt + (size_t)((b * 4 + kvh) * 128) * SEQ;
#pragma unroll
  for (int rep = 0; rep < 8; ++rep) {
    int lin = rep * 2048 + t * 8;
    int d = lin >> 7, sb = lin & 127;
    short8 o;
#pragma unroll
    for (int j = 0; j < 8; ++j) o[j] = tile[(sb + j) * 137 + d];
    *(short8*)(dst + (size_t)d * SEQ + s0 + sb) = o;
  }
}

// ---------------- flash attention (causal, GQA), 32x32 MFMA ----------------
// R14-proven structure; this round: max3-tree lmax + tree-sum lsum (depth cut
// on the softmax critical path).
__global__ __launch_bounds__(256, 2) void k_attn(const short* __restrict__ qkv,
                                                 const short* __restrict__ vt,
                                                 short* __restrict__ outp) {
  __shared__ short Ks[2][64 * 128];
  __shared__ short Vs[2][128 * 64];
  const int t = threadIdx.x, l = t & 63, w = t >> 6;
  const int wr = w >> 1, wk = w & 1;
  const int h = blockIdx.y, b = blockIdx.z;
  const int kvh = h >> 2;
  const int lo5 = l & 31, hi = l >> 5;

  const int kkey = t >> 4, kd8 = t & 15;
  const int vdd = t >> 3, vs8 = t & 7;
  const short* kbase = qkv + (size_t)(b * SEQ) * LDQKV + 2048 + kvh * HD;
  const short* vbase = vt + (size_t)((b * 4 + kvh) * 128) * SEQ;

  auto stageKV = [&](int buf, int it) {
    const int kt = it * 64;
    short* kdst = &Ks[buf][w * 512];
    short* vdst = &Vs[buf][w * 512];
#pragma unroll
    for (int i = 0; i < 4; ++i) {
      int key = i * 16 + kkey;
      int sd = (kd8 ^ (key & 15)) * 8;
      gload_lds16(kbase + (size_t)(kt + key) * LDQKV + sd, kdst + i * 2048);
    }
#pragma unroll
    for (int i = 0; i < 4; ++i) {
      int d = i * 32 + vdd;
      int ss = (vs8 ^ (d & 7)) * 8;
      gload_lds16(vbase + (size_t)d * SEQ + kt + ss, vdst + i * 2048);
    }
  };

  int koff[8], voff[4][2];
#pragma unroll
  for (int s = 0; s < 8; ++s)
    koff[s] = (wk * 32 + lo5) * 128 + (((hi + 2 * s) ^ (l & 15)) * 8);
#pragma unroll
  for (int db = 0; db < 4; ++db)
#pragma unroll
    for (int s = 0; s < 2; ++s)
      voff[db][s] =
          (db * 32 + lo5) * 64 + (((4 * wk + hi + 2 * s) ^ (l & 7)) * 8);
  const int kbloc = wk * 32 + 4 * hi;
  const int qloc = wr * 32 + lo5;

  for (int part = 0; part < 2; ++part) {
    const int qt = part ? (31 - (int)blockIdx.x) : (int)blockIdx.x;
    const int q0 = qt * 64;

    short8 qf[8];
    {
      const short* qrow =
          qkv + (size_t)(b * SEQ + q0 + wr * 32 + lo5) * LDQKV + h * HD;
#pragma unroll
      for (int s = 0; s < 8; ++s)
        qf[s] = *(const short8*)(qrow + s * 16 + hi * 8);
    }

    f32x16 of[4] = {};
    float mrun = 0.f, lsum = 0.f;

    const int nt = qt + 1;
    stageKV(0, 0);
    __syncthreads();

    for (int it = 0; it < nt; ++it) {
      const int buf = it & 1;
      if (it + 1 < nt) stageKV(buf ^ 1, it + 1);
      const short* KsC = Ks[buf];
      const short* VsC = Vs[buf];

      f32x16 sca = {}, scb = {};
      __builtin_amdgcn_s_setprio(1);
#pragma unroll
      for (int s = 0; s < 4; ++s) {
        short8 kf0 = *(const short8*)(KsC + koff[2 * s]);
        short8 kf1 = *(const short8*)(KsC + koff[2 * s + 1]);
        sca = mfma32(kf0, qf[2 * s], sca);
        scb = mfma32(kf1, qf[2 * s + 1], scb);
      }
      __builtin_amdgcn_s_setprio(0);
      f32x16 sc = sca + scb;

      if (it == nt - 1) {
#pragma unroll
        for (int r = 0; r < 16; ++r) {
          const int off = (r & 3) + 8 * (r >> 2);
          if (kbloc + off > qloc) sc[r] = -1e30f;
        }
      }

      // max3-tree local max (7 ops, depth 3; clang fuses to v_max3_f32)
      float m0_ = fmaxf(fmaxf(sc[0], sc[1]), sc[2]);
      float m1_ = fmaxf(fmaxf(sc[3], sc[4]), sc[5]);
      float m2_ = fmaxf(fmaxf(sc[6], sc[7]), sc[8]);
      float m3_ = fmaxf(fmaxf(sc[9], sc[10]), sc[11]);
      float m4_ = fmaxf(fmaxf(sc[12], sc[13]), sc[14]);
      float lmax = fmaxf(fmaxf(fmaxf(m0_, m1_), m2_),
                         fmaxf(fmaxf(m3_, m4_), sc[15]));
      if (__any(lmax > mrun + 8.f)) {
        float mx = fmaxf(lmax, __shfl_xor(lmax, 32));
        float mm = fmaxf(mrun, mx);
        float rs = fexp2(mrun - mm);
        mrun = mm;
        lsum *= rs;
#pragma unroll
        for (int db = 0; db < 4; ++db)
#pragma unroll
          for (int r = 0; r < 16; ++r) of[db][r] *= rs;
      }

      float p[16];
#pragma unroll
      for (int r = 0; r < 16; ++r) p[r] = fexp2(sc[r] - mrun);
      // tree-sum (depth 4) instead of 16-deep serial chain
      {
        float q0_ = (p[0] + p[1]) + (p[2] + p[3]);
        float q1_ = (p[4] + p[5]) + (p[6] + p[7]);
        float q2_ = (p[8] + p[9]) + (p[10] + p[11]);
        float q3_ = (p[12] + p[13]) + (p[14] + p[15]);
        lsum += (q0_ + q1_) + (q2_ + q3_);
      }
      unsigned int pk[8];
#pragma unroll
      for (int j = 0; j < 8; ++j) pk[j] = cvt_pk(p[2 * j], p[2 * j + 1]);

      unsigned int s0 = hi ? pk[0] : pk[2];
      unsigned int s1 = hi ? pk[1] : pk[3];
      unsigned int s2 = hi ? pk[4] : pk[6];
      unsigned int s3 = hi ? pk[5] : pk[7];
      unsigned int x0 = __shfl_xor(s0, 32);
      unsigned int x1 = __shfl_xor(s1, 32);
      unsigned int x2 = __shfl_xor(s2, 32);
      unsigned int x3 = __shfl_xor(s3, 32);
      u32x4 b0w, b1w;
      b0w.x = hi ? x0 : pk[0];
      b0w.y = hi ? x1 : pk[1];
      b0w.z = hi ? pk[2] : x0;
      b0w.w = hi ? pk[3] : x1;
      b1w.x = hi ? x2 : pk[4];
      b1w.y = hi ? x3 : pk[5];
      b1w.z = hi ? pk[6] : x2;
      b1w.w = hi ? pk[7] : x3;
      short8 pb[2] = {__builtin_bit_cast(short8, b0w),
                      __builtin_bit_cast(short8, b1w)};

      __builtin_amdgcn_s_setprio(1);
#pragma unroll
      for (int s = 0; s < 2; ++s)
#pragma unroll
        for (int db = 0; db < 4; ++db) {
          short8 vf = *(const short8*)(VsC + voff[db][s]);
          of[db] = mfma32(vf, pb[s], of[db]);
        }
      __builtin_amdgcn_s_setprio(0);
      __syncthreads();
    }

    lsum += __shfl_xor(lsum, 32);
    float* og = (float*)Ks;
    float* sg = (float*)Vs;
    if (wk == 1) {
#pragma unroll
      for (int db = 0; db < 4; ++db)
#pragma unroll
        for (int r4 = 0; r4 < 4; ++r4) {
          int g = db * 4 + r4;
          f32x4 v;
#pragma unroll
          for (int j = 0; j < 4; ++j) v[j] = of[db][r4 * 4 + j];
          *(f32x4*)&og[wr * 4096 + l * 64 + ((g ^ (l & 15)) * 4)] = v;
        }
      sg[wr * 64 + l] = mrun;
      sg[128 + wr * 64 + l] = lsum;
    }
    __syncthreads();
    if (wk == 0) {
      float m1 = sg[wr * 64 + l];
      float l1 = sg[128 + wr * 64 + l];
      float mt = fmaxf(mrun, m1);
      float r0 = fexp2(mrun - mt), r1 = fexp2(m1 - mt);
      float inv = 1.0f / (lsum * r0 + l1 * r1);
      short* ob =
          outp + (size_t)(b * SEQ + q0 + wr * 32 + lo5) * 2048 + h * HD;
#pragma unroll
      for (int db = 0; db < 4; ++db) {
#pragma unroll
        for (int r4 = 0; r4 < 4; ++r4) {
          int g = db * 4 + r4;
          f32x4 o1 = *(const f32x4*)&og[wr * 4096 + l * 64 +
                                        ((g ^ (l & 15)) * 4)];
          u32x2 pko;
          float v0 = (of[db][r4 * 4 + 0] * r0 + o1[0] * r1) * inv;
          float v1 = (of[db][r4 * 4 + 1] * r0 + o1[1] * r1) * inv;
          float v2 = (of[db][r4 * 4 + 2] * r0 + o1[2] * r1) * inv;
          float v3 = (of[db][r4 * 4 + 3] * r0 + o1[3] * r1) * inv;
          pko.x = cvt_pk(v0, v1);
          pko.y = cvt_pk(v2, v3);
          *(u32x2*)(ob + db * 32 + 8 * r4 + 4 * hi) = pko;
        }
      }
    }
    __syncthreads();
  }
}

extern "C" void kernel_launch(void* const* d_in, const int* in_sizes, int n_in,
                              void* d_out, int out_size, void* d_ws,
                              size_t ws_size, hipStream_t stream) {
  const float* x = (const float*)d_in[0];
  const float* wq = (const float*)d_in[1];
  const float* wk = (const float*)d_in[2];
  const float* wv = (const float*)d_in[3];
  const float* wo = (const float*)d_in[4];
  const float* fc = (const float*)d_in[5];
  const float* fs = (const float*)d_in[6];

  char* ws = (char*)d_ws;
  short* xb = (short*)(ws);                           // [4096][2048] 16MB
  short* wT = (short*)(ws + (16ull << 20));           // [3072][2048] 12MB
  short* woT = (short*)(ws + (28ull << 20));          // [2048][2048] 8MB
  short* qkvb = (short*)(ws + (36ull << 20));         // [4096][3072] 24MB
  short* vtb = (short*)(ws + (16ull << 20));          // alias wT (dead) 4MB
  short* attn = (short*)(ws);                         // alias xb (dead) 16MB

  k_prep<<<6656, 256, 0, stream>>>(x, wq, wk, wv, wo, xb, wT, woT);
  k_gemmQ<<<256, 512, 0, stream>>>(xb, wT, qkvb, fc, fs);
  k_vt<<<128, 256, 0, stream>>>(qkvb, vtb);
  k_attn<<<dim3(16, 16, 2), 256, 0, stream>>>(qkvb, vtb, attn);
  k_gemm256<1, 1, 0><<<256, 512, 0, stream>>>(attn, woT, d_out, nullptr,
                                              nullptr, 4096, 2048, 2048);
}